// Round 4
// baseline (2802.350 us; speedup 1.0000x reference)
//
#include <hip/hip_runtime.h>
#include <math.h>

#define HW 65536
#define XSTR 136   // shorts per px row (16B-aligned stride)
#define T_TILES 4

typedef short short8 __attribute__((ext_vector_type(8)));
typedef float f32x4 __attribute__((ext_vector_type(4)));

__device__ __forceinline__ float2 cmul(float2 a, float2 b){
  return make_float2(a.x*b.x - a.y*b.y, a.x*b.y + a.y*b.x);
}

__device__ __forceinline__ unsigned short f2bf(float f){
  unsigned u = __float_as_uint(f);
  u += 0x7fff + ((u >> 16) & 1);
  return (unsigned short)(u >> 16);
}
__device__ __forceinline__ float bf2f(unsigned short h){
  unsigned u = ((unsigned)h) << 16;
  return __uint_as_float(u);
}

// ---------------- weight prep: fp32 -> bf16 hi/lo, 8 matrices ----------------
// order: qkv0,qkv1,qkv2, kv0,kv1, q1, q2, projf
__global__ __launch_bounds__(256) void wprep_k(
    const float* __restrict__ qkv_w, const float* __restrict__ kv_w,
    const float* __restrict__ q1_w, const float* __restrict__ q2_w,
    const float* __restrict__ projf_w,
    unsigned short* __restrict__ WHp, unsigned short* __restrict__ WLp)
{
  int i = blockIdx.x*256 + threadIdx.x;   // 0..131071
  int mat = i >> 14, idx = i & 16383;
  const float* src = mat < 3 ? qkv_w + mat*16384
                   : mat < 5 ? kv_w + (mat-3)*16384
                   : mat == 5 ? q1_w : mat == 6 ? q2_w : projf_w;
  float v = src[idx];
  unsigned short h = f2bf(v);
  WHp[i] = h;
  WLp[i] = f2bf(v - bf2f(h));
}

// ---------------- fused conv1x1 via split-bf16 MFMA ----------------
// Y[b, o, oc, px] = act(sum_k W[o][oc,k] X[b,k,px]) (+R). Cin=128.
// Block: 128oc x 64px tile, T_TILES consecutive px tiles, NOUT outputs.
// Software pipeline: prefetch tile t+1 globals during tile t MFMA.
template<int NOUT>
__global__ __launch_bounds__(256,4) void convN_mfma(
    const float* __restrict__ X, size_t bsX,
    const unsigned short* __restrict__ WH, const unsigned short* __restrict__ WL,
    size_t bsW,
    float* __restrict__ Y, size_t bsY, size_t osY,
    const float* __restrict__ R, size_t bsR,
    int act)
{
  __shared__ unsigned short xh[64*XSTR];
  __shared__ unsigned short xl[64*XSTR];
  const int t = threadIdx.x, l = t & 63, w = t >> 6;
  const int b = blockIdx.z;
  const float* Xb = X + (size_t)b*bsX;
  const unsigned short* WHb = WH + (size_t)b*bsW;
  const unsigned short* WLb = WL + (size_t)b*bsW;
  float* Yb = Y + (size_t)b*bsY;
  const float* Rb = R ? (R + (size_t)b*bsR) : nullptr;

  const int spx = (t & 15) << 2;   // staging px 0..60
  const int sk  = t >> 4;          // staging k sub 0..15
  const int swz = (t & 7) << 3;
  const int kg  = (l >> 4) << 3;
  const size_t pxB = (size_t)blockIdx.x * (64*T_TILES);

  float4 r[8];
  #pragma unroll
  for (int i=0;i<8;i++) r[i] = *(const float4*)(Xb + (size_t)(i*16+sk)*HW + pxB + spx);

  for (int tt=0; tt<T_TILES; ++tt){
    const size_t px0 = pxB + tt*64;
    // ---- convert & stage current tile ----
    #pragma unroll
    for (int i=0;i<8;i++){
      const int kk = (i*16 + sk) ^ swz;
      float f[4] = {r[i].x, r[i].y, r[i].z, r[i].w};
      #pragma unroll
      for (int j=0;j<4;j++){
        unsigned short hb = f2bf(f[j]);
        xh[(spx+j)*XSTR + kk] = hb;
        xl[(spx+j)*XSTR + kk] = f2bf(f[j] - bf2f(hb));
      }
    }
    __syncthreads();
    // ---- prefetch next tile (latency hidden under MFMA) ----
    if (tt+1 < T_TILES){
      #pragma unroll
      for (int i=0;i<8;i++) r[i] = *(const float4*)(Xb + (size_t)(i*16+sk)*HW + px0 + 64 + spx);
    }
    // ---- per-output GEMM on staged tile ----
    #pragma unroll
    for (int o=0;o<NOUT;o++){
      const unsigned short* WHo = WHb + o*16384;
      const unsigned short* WLo = WLb + o*16384;
      f32x4 acc[2][4];
      #pragma unroll
      for (int m=0;m<2;m++)
        #pragma unroll
        for (int n=0;n<4;n++) acc[m][n] = (f32x4){0.f,0.f,0.f,0.f};
      #pragma unroll
      for (int ks=0;ks<4;ks++){
        short8 whi[2], wlo[2];
        #pragma unroll
        for (int m=0;m<2;m++){
          const int row = (w<<5) + 16*m + (l & 15);
          whi[m] = *(const short8*)(WHo + row*128 + 32*ks + kg);
          wlo[m] = *(const short8*)(WLo + row*128 + 32*ks + kg);
        }
        #pragma unroll
        for (int n=0;n<4;n++){
          const int px = 16*n + (l & 15);
          const int off = px*XSTR + ((32*ks + kg) ^ (((px>>2)&7)<<3));
          short8 bh = *(short8*)&xh[off];
          short8 bl = *(short8*)&xl[off];
          #pragma unroll
          for (int m=0;m<2;m++){
            acc[m][n] = __builtin_amdgcn_mfma_f32_16x16x32_bf16(whi[m], bh, acc[m][n], 0,0,0);
            acc[m][n] = __builtin_amdgcn_mfma_f32_16x16x32_bf16(wlo[m], bh, acc[m][n], 0,0,0);
            acc[m][n] = __builtin_amdgcn_mfma_f32_16x16x32_bf16(whi[m], bl, acc[m][n], 0,0,0);
          }
        }
      }
      // ---- epilogue ----
      float* Yo = Yb + o*osY;
      #pragma unroll
      for (int m=0;m<2;m++){
        const int ocb = (w<<5) + 16*m + ((l>>4)<<2);
        #pragma unroll
        for (int n=0;n<4;n++){
          const size_t pxw = px0 + 16*n + (l & 15);
          #pragma unroll
          for (int rr=0;rr<4;rr++){
            float v = acc[m][n][rr];
            if (act==1) v = 0.5f*v*(1.f + erff(v*0.70710678118654752440f));
            size_t off = (size_t)(ocb + rr)*HW + pxw;
            if (Rb) v += Rb[off];
            Yo[off] = v;
          }
        }
      }
    }
    if (tt+1 < T_TILES) __syncthreads();
  }
}

// ---------------- depthwise 3x3, SAME ----------------
__global__ __launch_bounds__(256) void dwconv3_k(
    const float* __restrict__ in, const float* __restrict__ w9,
    float* __restrict__ out, int C)
{
  __shared__ float tl[34][34];
  int z = blockIdx.z;
  int c = z % C;
  size_t base = (size_t)z * HW;
  int x0 = blockIdx.x*32, y0 = blockIdx.y*32;
  int t = threadIdx.x;
  for (int idx=t; idx<34*34; idx+=256){
    int r = idx/34, cc = idx - r*34;
    int gy = y0 + r - 1, gx = x0 + cc - 1;
    float v = 0.f;
    if ((unsigned)gy < 256u && (unsigned)gx < 256u) v = in[base + (size_t)gy*256 + gx];
    tl[r][cc] = v;
  }
  float wv[9];
  #pragma unroll
  for (int i=0;i<9;i++) wv[i] = w9[c*9+i];
  __syncthreads();
  int col = t & 31, r0 = t >> 5;
  #pragma unroll
  for (int kq=0;kq<4;kq++){
    int r = r0 + kq*8;
    float acc = 0.f;
    #pragma unroll
    for (int dy=0;dy<3;dy++)
      #pragma unroll
      for (int dx=0;dx<3;dx++)
        acc = fmaf(wv[dy*3+dx], tl[r+dy][col+dx], acc);
    out[base + (size_t)(y0+r)*256 + x0 + col] = acc;
  }
}

// ---------------- per-channel 1/max(||row||,eps) ----------------
__global__ __launch_bounds__(256) void colnorm_k(
    const float* __restrict__ in, float* __restrict__ rnorm, int chOff)
{
  int ch = blockIdx.x, b = blockIdx.y;
  const float* p = in + ((size_t)b*128 + ch)*HW;
  int t = threadIdx.x;
  float ss = 0.f;
  for (int i = t*4; i < HW; i += 256*4){
    float4 v = *(const float4*)(p + i);
    ss += v.x*v.x + v.y*v.y + v.z*v.z + v.w*v.w;
  }
  #pragma unroll
  for (int o=32;o>0;o>>=1) ss += __shfl_down(ss, o);
  __shared__ float red[4];
  if ((t&63)==0) red[t>>6] = ss;
  __syncthreads();
  if (t==0){
    float s = red[0]+red[1]+red[2]+red[3];
    rnorm[b*256 + chOff + ch] = 1.f/fmaxf(sqrtf(s), 1e-12f);
  }
}

// ---------------- partial Gram ----------------
__global__ __launch_bounds__(256) void qk_gram_k(
    const float* __restrict__ q, const float* __restrict__ k, float* __restrict__ Gp)
{
  __shared__ float qs[16][65], ks[16][65];
  int s = blockIdx.x, h = blockIdx.y, b = blockIdx.z;
  int t = threadIdx.x;
  int c = t >> 4, d = t & 15;
  const float* qb = q + ((size_t)b*128 + h*16)*HW + (size_t)s*1024;
  const float* kb = k + ((size_t)b*128 + h*16)*HW + (size_t)s*1024;
  float acc = 0.f;
  for (int n0=0;n0<1024;n0+=64){
    #pragma unroll
    for (int it=0;it<4;it++){
      int idx = it*256 + t;
      int row = idx >> 6, col = idx & 63;
      qs[row][col] = qb[(size_t)row*HW + n0 + col];
      ks[row][col] = kb[(size_t)row*HW + n0 + col];
    }
    __syncthreads();
    #pragma unroll
    for (int nn=0;nn<64;nn++) acc = fmaf(qs[c][nn], ks[d][nn], acc);
    __syncthreads();
  }
  Gp[(((size_t)b*8 + h)*64 + s)*256 + t] = acc;
}

// ---------------- combine, softmax, W_eff (bf16 hi/lo out) ----------------
__global__ __launch_bounds__(256) void attn_weff_k(
    const float* __restrict__ Gp, const float* __restrict__ rnorm,
    const float* __restrict__ temp, const float* __restrict__ proj_w,
    unsigned short* __restrict__ WeffH, unsigned short* __restrict__ WeffL)
{
  int b = blockIdx.x, t = threadIdx.x;
  __shared__ float G[8][16][16];
  __shared__ float A[8][16][16];
  for (int e = t; e < 2048; e += 256){
    int h = e >> 8, cd = e & 255;
    int c = cd >> 4, d = cd & 15;
    const float* gp = Gp + (((size_t)b*8 + h)*64)*256 + cd;
    float sum = 0.f;
    for (int s2=0;s2<64;s2++) sum += gp[(size_t)s2*256];
    G[h][c][d] = sum * rnorm[b*256 + h*16 + c] * rnorm[b*256 + 128 + h*16 + d] * temp[h];
  }
  __syncthreads();
  if (t < 128){
    int h = t >> 4, c = t & 15;
    float m = -1e30f;
    for (int d=0;d<16;d++) m = fmaxf(m, G[h][c][d]);
    float e[16], ssum = 0.f;
    for (int d=0;d<16;d++){ e[d] = expf(G[h][c][d]-m); ssum += e[d]; }
    float inv = 1.f/ssum;
    for (int d=0;d<16;d++) A[h][c][d] = e[d]*inv;
  }
  __syncthreads();
  for (int idx = t; idx < 16384; idx += 256){
    int o = idx >> 7, hd = idx & 127;
    int h = hd >> 4, d = hd & 15;
    float acc = 0.f;
    #pragma unroll
    for (int c=0;c<16;c++) acc = fmaf(proj_w[o*128 + h*16 + c], A[h][c][d], acc);
    unsigned short hb = f2bf(acc);
    WeffH[(size_t)b*16384 + idx] = hb;
    WeffL[(size_t)b*16384 + idx] = f2bf(acc - bf2f(hb));
  }
}

// ---------------- 8x8 circular convolution, register-blocked ----------------
__global__ __launch_bounds__(256) void patch_circ_k(
    const float* __restrict__ vf, const float* __restrict__ kf, float* __restrict__ out)
{
  __shared__ float vs[32*68];
  __shared__ float ks2[32*68];
  size_t base = (size_t)blockIdx.y*HW + (size_t)blockIdx.x*2048;
  int t = threadIdx.x;
  #pragma unroll
  for (int it=0; it<2; it++){
    int idx = it*256 + t;
    int row = idx >> 6;
    int c4  = (idx & 63) << 2;
    float4 v  = *(const float4*)(vf + base + (size_t)row*256 + c4);
    float4 kv = *(const float4*)(kf + base + (size_t)row*256 + c4);
    int p = c4 >> 3, j0 = c4 & 7;
    *(float4*)&vs [p*68 + row*8 + j0] = v;
    *(float4*)&ks2[p*68 + row*8 + j0] = kv;
  }
  __syncthreads();
  int p = t & 31, pr = t >> 5;
  float acc[8];
  #pragma unroll
  for (int q=0;q<8;q++) acc[q]=0.f;
  #pragma unroll
  for (int i=0;i<8;i++){
    float4 va = *(float4*)&vs[p*68 + i*8];
    float4 vb = *(float4*)&vs[p*68 + i*8 + 4];
    int kr = (pr - i) & 7;
    float4 ka = *(float4*)&ks2[p*68 + kr*8];
    float4 kb = *(float4*)&ks2[p*68 + kr*8 + 4];
    float vv[8]={va.x,va.y,va.z,va.w,vb.x,vb.y,vb.z,vb.w};
    float kk[8]={ka.x,ka.y,ka.z,ka.w,kb.x,kb.y,kb.z,kb.w};
    #pragma unroll
    for (int q=0;q<8;q++)
      #pragma unroll
      for (int j=0;j<8;j++)
        acc[q] = fmaf(vv[j], kk[(q-j)&7], acc[q]);
  }
  float* op = out + base + (size_t)pr*256 + p*8;
  *(float4*)op     = make_float4(acc[0],acc[1],acc[2],acc[3]);
  *(float4*)(op+4) = make_float4(acc[4],acc[5],acc[6],acc[7]);
}

// ---------------- 256-pt Stockham FFT along rows ----------------
template<bool IN_REAL, bool OUT_REAL>
__global__ __launch_bounds__(64) void fft256_rows(
    const float* __restrict__ in, float* __restrict__ out, float dir, float scale)
{
  __shared__ float2 buf[2][256];
  __shared__ float2 tw[128];
  int t = threadIdx.x;
  size_t row = blockIdx.x;
  for (int i = t; i < 128; i += 64){
    float ang = 6.283185307179586477f * (float)i / 256.f;
    float s, c;
    sincosf(ang, &s, &c);
    tw[i] = make_float2(c, dir*s);
  }
  if (IN_REAL){
    const float* p = in + row*256;
    for (int i=t;i<256;i+=64) buf[0][i] = make_float2(p[i], 0.f);
  } else {
    const float2* p = ((const float2*)in) + row*256;
    for (int i=t;i<256;i+=64) buf[0][i] = p[i];
  }
  int cur = 0, m = 1;
  for (int st=0; st<8; st++){
    __syncthreads();
    #pragma unroll
    for (int p2=0;p2<2;p2++){
      int bf = t + (p2<<6);
      int k = bf & (m-1);
      int jm = bf - k;
      float2 a = buf[cur][k + jm];
      float2 c = buf[cur][k + jm + 128];
      float2 w = tw[jm];
      float2 sm = make_float2(a.x+c.x, a.y+c.y);
      float2 df = make_float2(a.x-c.x, a.y-c.y);
      buf[cur^1][k + 2*jm]     = sm;
      buf[cur^1][k + 2*jm + m] = cmul(w, df);
    }
    cur ^= 1; m <<= 1;
  }
  __syncthreads();
  if (OUT_REAL){
    float* p = out + row*256;
    for (int i=t;i<256;i+=64) p[i] = buf[cur][i].x * scale;
  } else {
    float2* p = ((float2*)out) + row*256;
    for (int i=t;i<256;i+=64){
      float2 v = buf[cur][i];
      p[i] = make_float2(v.x*scale, v.y*scale);
    }
  }
}

// ---------------- complex 256x256 per-plane transpose ----------------
__global__ __launch_bounds__(256) void transpose_c_k(
    const float2* __restrict__ in, float2* __restrict__ out)
{
  __shared__ float2 tile[32][33];
  int plane = blockIdx.z;
  int x0 = blockIdx.x*32, y0 = blockIdx.y*32;
  const float2* ip = in + (size_t)plane*HW;
  float2* op = out + (size_t)plane*HW;
  int tx = threadIdx.x & 31, ty = threadIdx.x >> 5;
  #pragma unroll
  for (int r=0;r<4;r++){
    int y = y0 + ty*4 + r;
    tile[ty*4+r][tx] = ip[(size_t)y*256 + x0 + tx];
  }
  __syncthreads();
  #pragma unroll
  for (int r=0;r<4;r++){
    int y = x0 + ty*4 + r;
    op[(size_t)y*256 + y0 + tx] = tile[tx][ty*4+r];
  }
}

// ---------------- channel LayerNorm * qf ----------------
__global__ __launch_bounds__(256) void ln_mul_k(
    const float* __restrict__ x, const float* __restrict__ qf,
    const float* __restrict__ lw, const float* __restrict__ lb,
    float* __restrict__ y)
{
  int b = blockIdx.y;
  size_t px0 = (size_t)blockIdx.x*64;
  int t = threadIdx.x;
  int px = t & 63, g = t >> 6;
  const float* xp = x + (size_t)b*8388608 + px0 + px;
  float vals[32];
  float s1 = 0.f, s2 = 0.f;
  #pragma unroll
  for (int i=0;i<32;i++){
    float v = xp[(size_t)(g*32+i)*HW];
    vals[i] = v; s1 += v; s2 += v*v;
  }
  __shared__ float r1[4][64], r2[4][64];
  r1[g][px] = s1; r2[g][px] = s2;
  __syncthreads();
  float S1 = r1[0][px]+r1[1][px]+r1[2][px]+r1[3][px];
  float S2 = r2[0][px]+r2[1][px]+r2[2][px]+r2[3][px];
  float mu = S1 * (1.f/128.f);
  float var = S2 * (1.f/128.f) - mu*mu;
  float rstd = rsqrtf(var + 1e-5f);
  const float* qp = qf + (size_t)b*8388608 + px0 + px;
  float* yp = y + (size_t)b*8388608 + px0 + px;
  #pragma unroll
  for (int i=0;i<32;i++){
    int c = g*32 + i;
    float v = (vals[i]-mu)*rstd*lw[c] + lb[c];
    yp[(size_t)c*HW] = v * qp[(size_t)c*HW];
  }
}

extern "C" void kernel_launch(void* const* d_in, const int* in_sizes, int n_in,
                              void* d_out, int out_size, void* d_ws, size_t ws_size,
                              hipStream_t stream)
{
  const float* x       = (const float*)d_in[0];
  const float* qkv_w   = (const float*)d_in[1];
  const float* qkv_dw  = (const float*)d_in[2];
  const float* proj_w  = (const float*)d_in[3];
  const float* q1_w    = (const float*)d_in[4];
  const float* q2_w    = (const float*)d_in[5];
  const float* kv_w    = (const float*)d_in[6];
  const float* kv_dw   = (const float*)d_in[7];
  const float* projf_w = (const float*)d_in[8];
  const float* temp    = (const float*)d_in[9];
  const float* ln_w    = (const float*)d_in[10];
  const float* ln_b    = (const float*)d_in[11];
  float* out = (float*)d_out;
  float* ws  = (float*)d_ws;

  const size_t P  = 33554432;   // 4*128*65536 floats
  const size_t CB = 8388608;    // per-batch stride
  float* A = ws;
  float* B = ws + P;
  float* C = ws + 2*P;
  float* rnorm = ws + 3*P;                 // 1024
  float* Gp    = rnorm + 1024;             // 524288
  unsigned short* WHp   = (unsigned short*)(Gp + 524288);  // 131072 shorts
  unsigned short* WLp   = WHp + 131072;
  unsigned short* WeffH = WLp + 131072;    // 65536 shorts
  unsigned short* WeffL = WeffH + 65536;

  dim3 cg(256,1,4); dim3 cb(256);
  dim3 dg(8,8,512); dim3 db(256);

  // ---- weight prep ----
  wprep_k<<<512,256,0,stream>>>(qkv_w, kv_w, q1_w, q2_w, projf_w, WHp, WLp);
  // ---- fused qkv conv: x -> A(q),B(k),C(v) ----
  convN_mfma<3><<<cg,cb,0,stream>>>(x, CB, WHp, WLp, 0, A, CB, P, nullptr, 0, 0);
  // ---- dw + norms + gram + softmax ----
  dwconv3_k<<<dg,db,0,stream>>>(A, qkv_dw + 0*1152, out, 128);   // q = out
  colnorm_k<<<dim3(128,4),256,0,stream>>>(out, rnorm, 0);
  dwconv3_k<<<dg,db,0,stream>>>(B, qkv_dw + 1*1152, A, 128);     // k = A
  colnorm_k<<<dim3(128,4),256,0,stream>>>(A, rnorm, 128);
  qk_gram_k<<<dim3(64,8,4),256,0,stream>>>(out, A, Gp);
  attn_weff_k<<<4,256,0,stream>>>(Gp, rnorm, temp, proj_w, WeffH, WeffL);
  dwconv3_k<<<dg,db,0,stream>>>(C, qkv_dw + 2*1152, B, 128);     // v = B
  // ---- attn out = Weff @ v -> C (per-batch weights) ----
  convN_mfma<1><<<cg,cb,0,stream>>>(B, CB, WeffH, WeffL, 16384, C, CB, 0, nullptr, 0, 0);
  // ---- fused kf/vf conv: C -> A(kf),B(vf) ----
  convN_mfma<2><<<cg,cb,0,stream>>>(C, CB, WHp + 3*16384, WLp + 3*16384, 0, A, CB, P, nullptr, 0, 0);
  dwconv3_k<<<dg,db,0,stream>>>(A, kv_dw + 0*1152, out, 128);    // kf = out
  dwconv3_k<<<dg,db,0,stream>>>(B, kv_dw + 1*1152, A, 128);      // vf = A
  // ---- patch circular conv -> out_1 = B ----
  patch_circ_k<<<dim3(32,512),256,0,stream>>>(A, out, B);
  // ---- forward FFT: x -> x_fftT in out ----
  for (int b=0;b<4;b++){
    fft256_rows<true,false><<<32768,64,0,stream>>>(x + (size_t)b*CB, A, -1.f, 1.f);
    transpose_c_k<<<dim3(8,8,128),256,0,stream>>>((const float2*)A, (float2*)(A + P/2));
    fft256_rows<false,true><<<32768,64,0,stream>>>(A + P/2, out + (size_t)b*CB, -1.f, 1.f);
  }
  // ---- gating convs ----
  convN_mfma<1><<<cg,cb,0,stream>>>(out, CB, WHp + 5*16384, WLp + 5*16384, 0, A, CB, 0, nullptr, 0, 1);
  convN_mfma<1><<<cg,cb,0,stream>>>(A, CB, WHp + 6*16384, WLp + 6*16384, 0, out, CB, 0, nullptr, 0, 0);
  // ---- inverse FFT: x_fft3T (out) -> qf (out) ----
  for (int b=0;b<4;b++){
    fft256_rows<true,false><<<32768,64,0,stream>>>(out + (size_t)b*CB, A, 1.f, 1.f/256.f);
    transpose_c_k<<<dim3(8,8,128),256,0,stream>>>((const float2*)A, (float2*)(A + P/2));
    fft256_rows<false,true><<<32768,64,0,stream>>>(A + P/2, out + (size_t)b*CB, 1.f, 1.f/256.f);
  }
  // ---- LayerNorm(out_1=B) * qf(out) -> A ----
  ln_mul_k<<<dim3(1024,4),256,0,stream>>>(B, out, ln_w, ln_b, A);
  // ---- final conv + residual (R = C) ----
  convN_mfma<1><<<cg,cb,0,stream>>>(A, CB, WHp + 7*16384, WLp + 7*16384, 0, out, CB, 0, C, CB, 0);
}

// Round 5
// 1950.049 us; speedup vs baseline: 1.4371x; 1.4371x over previous
//
#include <hip/hip_runtime.h>
#include <math.h>

#define HW 65536
#define XSTR 136   // shorts per px row (16B-aligned stride)
#define T_TILES 8

typedef short short8 __attribute__((ext_vector_type(8)));
typedef float f32x4 __attribute__((ext_vector_type(4)));

__device__ __forceinline__ float2 cmul(float2 a, float2 b){
  return make_float2(a.x*b.x - a.y*b.y, a.x*b.y + a.y*b.x);
}

__device__ __forceinline__ unsigned short f2bf(float f){
  unsigned u = __float_as_uint(f);
  u += 0x7fff + ((u >> 16) & 1);
  return (unsigned short)(u >> 16);
}
__device__ __forceinline__ float bf2f(unsigned short h){
  unsigned u = ((unsigned)h) << 16;
  return __uint_as_float(u);
}

// ---------------- weight prep: fp32 -> bf16 hi/lo, 8 matrices ----------------
// order: qkv0,qkv1,qkv2, kv0,kv1, q1, q2, projf
__global__ __launch_bounds__(256) void wprep_k(
    const float* __restrict__ qkv_w, const float* __restrict__ kv_w,
    const float* __restrict__ q1_w, const float* __restrict__ q2_w,
    const float* __restrict__ projf_w,
    unsigned short* __restrict__ WHp, unsigned short* __restrict__ WLp)
{
  int i = blockIdx.x*256 + threadIdx.x;   // 0..131071
  int mat = i >> 14, idx = i & 16383;
  const float* src = mat < 3 ? qkv_w + mat*16384
                   : mat < 5 ? kv_w + (mat-3)*16384
                   : mat == 5 ? q1_w : mat == 6 ? q2_w : projf_w;
  float v = src[idx];
  unsigned short h = f2bf(v);
  WHp[i] = h;
  WLp[i] = f2bf(v - bf2f(h));
}

// ---------------- conv1x1 via split-bf16 MFMA, T_TILES px pipeline ----------------
// Y[b,oc,px] = act(sum_k W[oc,k] X[b,k,px]) (+R). Cin=128. W hi/lo regs once/block.
__global__ __launch_bounds__(256,2) void convT_mfma(
    const float* __restrict__ X, size_t bsX,
    const unsigned short* __restrict__ WH, const unsigned short* __restrict__ WL,
    size_t bsW,
    float* __restrict__ Y, size_t bsY,
    const float* __restrict__ R, size_t bsR,
    int act)
{
  __shared__ unsigned short xh[64*XSTR];
  __shared__ unsigned short xl[64*XSTR];
  const int t = threadIdx.x, l = t & 63, w = t >> 6;
  const int b = blockIdx.z;
  const float* Xb = X + (size_t)b*bsX;
  float* Yb = Y + (size_t)b*bsY;
  const float* Rb = R ? (R + (size_t)b*bsR) : nullptr;

  const int spx = (t & 15) << 2;   // staging px 0..60
  const int sk  = t >> 4;          // staging k 0..15 (step 16)
  const int swz = (t & 7) << 3;
  const int kg  = (l >> 4) << 3;

  // ---- W fragments once per block ----
  short8 whi[2][4], wlo[2][4];
  {
    const unsigned short* WHb = WH + (size_t)b*bsW;
    const unsigned short* WLb = WL + (size_t)b*bsW;
    #pragma unroll
    for (int m=0;m<2;m++){
      const int row = (w<<5) + 16*m + (l & 15);
      #pragma unroll
      for (int ks=0;ks<4;ks++){
        whi[m][ks] = *(const short8*)(WHb + row*128 + 32*ks + kg);
        wlo[m][ks] = *(const short8*)(WLb + row*128 + 32*ks + kg);
      }
    }
  }

  const size_t pxB = (size_t)blockIdx.x * (64*T_TILES);
  float4 r[8];
  #pragma unroll
  for (int i=0;i<8;i++) r[i] = *(const float4*)(Xb + (size_t)(i*16+sk)*HW + pxB + spx);

  for (int tt=0; tt<T_TILES; ++tt){
    const size_t px0 = pxB + tt*64;
    // ---- convert & stage current tile ----
    #pragma unroll
    for (int i=0;i<8;i++){
      const int kk = (i*16 + sk) ^ swz;
      float f[4] = {r[i].x, r[i].y, r[i].z, r[i].w};
      #pragma unroll
      for (int j=0;j<4;j++){
        unsigned short hb = f2bf(f[j]);
        xh[(spx+j)*XSTR + kk] = hb;
        xl[(spx+j)*XSTR + kk] = f2bf(f[j] - bf2f(hb));
      }
    }
    __syncthreads();
    // ---- prefetch next tile (hidden under MFMA) ----
    if (tt+1 < T_TILES){
      #pragma unroll
      for (int i=0;i<8;i++) r[i] = *(const float4*)(Xb + (size_t)(i*16+sk)*HW + px0 + 64 + spx);
    }
    // ---- MFMA on staged tile ----
    f32x4 acc[2][4];
    #pragma unroll
    for (int m=0;m<2;m++)
      #pragma unroll
      for (int n=0;n<4;n++) acc[m][n] = (f32x4){0.f,0.f,0.f,0.f};
    #pragma unroll
    for (int ks=0;ks<4;ks++){
      #pragma unroll
      for (int n=0;n<4;n++){
        const int px = 16*n + (l & 15);
        const int off = px*XSTR + ((32*ks + kg) ^ (((px>>2)&7)<<3));
        short8 bh = *(short8*)&xh[off];
        short8 bl = *(short8*)&xl[off];
        #pragma unroll
        for (int m=0;m<2;m++){
          acc[m][n] = __builtin_amdgcn_mfma_f32_16x16x32_bf16(whi[m][ks], bh, acc[m][n], 0,0,0);
          acc[m][n] = __builtin_amdgcn_mfma_f32_16x16x32_bf16(wlo[m][ks], bh, acc[m][n], 0,0,0);
          acc[m][n] = __builtin_amdgcn_mfma_f32_16x16x32_bf16(whi[m][ks], bl, acc[m][n], 0,0,0);
        }
      }
    }
    __syncthreads();   // all LDS reads done; epilogue overlaps next staging
    // ---- epilogue ----
    #pragma unroll
    for (int m=0;m<2;m++){
      const int ocb = (w<<5) + 16*m + ((l>>4)<<2);
      #pragma unroll
      for (int n=0;n<4;n++){
        const size_t pxw = px0 + 16*n + (l & 15);
        #pragma unroll
        for (int rr=0;rr<4;rr++){
          float v = acc[m][n][rr];
          if (act==1) v = 0.5f*v*(1.f + erff(v*0.70710678118654752440f));
          size_t off = (size_t)(ocb + rr)*HW + pxw;
          if (Rb) v += Rb[off];
          Yb[off] = v;
        }
      }
    }
  }
}

// ---------------- depthwise 3x3, SAME — full-row streaming tiles ----------------
__global__ __launch_bounds__(256,4) void dwconv3_row_k(
    const float* __restrict__ in, const float* __restrict__ w9,
    float* __restrict__ out)
{
  __shared__ float tl[34][256];
  int z = blockIdx.x;                // plane (b*128+c)
  int cch = z & 127;
  int y0 = blockIdx.y * 32;
  size_t base = (size_t)z * HW;
  int t = threadIdx.x;
  float wv[9];
  #pragma unroll
  for (int i=0;i<9;i++) wv[i] = w9[cch*9+i];
  for (int idx = t; idx < 34*64; idx += 256){
    int r = idx >> 6, c4 = (idx & 63) << 2;
    int gy = y0 + r - 1;
    float4 v = make_float4(0.f,0.f,0.f,0.f);
    if ((unsigned)gy < 256u) v = *(const float4*)(in + base + (size_t)gy*256 + c4);
    *(float4*)&tl[r][c4] = v;
  }
  __syncthreads();
  const int ct = t;                  // column 0..255
  for (int r = 0; r < 32; ++r){
    float acc = 0.f;
    #pragma unroll
    for (int dy=0; dy<3; dy++){
      float a  = (ct>0)   ? tl[r+dy][ct-1] : 0.f;
      float bm = tl[r+dy][ct];
      float c2 = (ct<255) ? tl[r+dy][ct+1] : 0.f;
      acc = fmaf(wv[dy*3+0], a, fmaf(wv[dy*3+1], bm, fmaf(wv[dy*3+2], c2, acc)));
    }
    out[base + (size_t)(y0+r)*256 + ct] = acc;
  }
}

// ---------------- per-channel 1/max(||row||,eps) ----------------
__global__ __launch_bounds__(256) void colnorm_k(
    const float* __restrict__ in, float* __restrict__ rnorm, int chOff)
{
  int ch = blockIdx.x, b = blockIdx.y;
  const float* p = in + ((size_t)b*128 + ch)*HW;
  int t = threadIdx.x;
  float ss = 0.f;
  for (int i = t*4; i < HW; i += 256*4){
    float4 v = *(const float4*)(p + i);
    ss += v.x*v.x + v.y*v.y + v.z*v.z + v.w*v.w;
  }
  #pragma unroll
  for (int o=32;o>0;o>>=1) ss += __shfl_down(ss, o);
  __shared__ float red[4];
  if ((t&63)==0) red[t>>6] = ss;
  __syncthreads();
  if (t==0){
    float s = red[0]+red[1]+red[2]+red[3];
    rnorm[b*256 + chOff + ch] = 1.f/fmaxf(sqrtf(s), 1e-12f);
  }
}

// ---------------- partial Gram ----------------
__global__ __launch_bounds__(256) void qk_gram_k(
    const float* __restrict__ q, const float* __restrict__ k, float* __restrict__ Gp)
{
  __shared__ float qs[16][65], ks[16][65];
  int s = blockIdx.x, h = blockIdx.y, b = blockIdx.z;
  int t = threadIdx.x;
  int c = t >> 4, d = t & 15;
  const float* qb = q + ((size_t)b*128 + h*16)*HW + (size_t)s*1024;
  const float* kb = k + ((size_t)b*128 + h*16)*HW + (size_t)s*1024;
  float acc = 0.f;
  for (int n0=0;n0<1024;n0+=64){
    #pragma unroll
    for (int it=0;it<4;it++){
      int idx = it*256 + t;
      int row = idx >> 6, col = idx & 63;
      qs[row][col] = qb[(size_t)row*HW + n0 + col];
      ks[row][col] = kb[(size_t)row*HW + n0 + col];
    }
    __syncthreads();
    #pragma unroll
    for (int nn=0;nn<64;nn++) acc = fmaf(qs[c][nn], ks[d][nn], acc);
    __syncthreads();
  }
  Gp[(((size_t)b*8 + h)*64 + s)*256 + t] = acc;
}

// ---------------- combine, softmax, W_eff (bf16 hi/lo out) ----------------
__global__ __launch_bounds__(256) void attn_weff_k(
    const float* __restrict__ Gp, const float* __restrict__ rnorm,
    const float* __restrict__ temp, const float* __restrict__ proj_w,
    unsigned short* __restrict__ WeffH, unsigned short* __restrict__ WeffL)
{
  int b = blockIdx.x, t = threadIdx.x;
  __shared__ float G[8][16][16];
  __shared__ float A[8][16][16];
  for (int e = t; e < 2048; e += 256){
    int h = e >> 8, cd = e & 255;
    int c = cd >> 4, d = cd & 15;
    const float* gp = Gp + (((size_t)b*8 + h)*64)*256 + cd;
    float sum = 0.f;
    for (int s2=0;s2<64;s2++) sum += gp[(size_t)s2*256];
    G[h][c][d] = sum * rnorm[b*256 + h*16 + c] * rnorm[b*256 + 128 + h*16 + d] * temp[h];
  }
  __syncthreads();
  if (t < 128){
    int h = t >> 4, c = t & 15;
    float m = -1e30f;
    for (int d=0;d<16;d++) m = fmaxf(m, G[h][c][d]);
    float e[16], ssum = 0.f;
    for (int d=0;d<16;d++){ e[d] = expf(G[h][c][d]-m); ssum += e[d]; }
    float inv = 1.f/ssum;
    for (int d=0;d<16;d++) A[h][c][d] = e[d]*inv;
  }
  __syncthreads();
  for (int idx = t; idx < 16384; idx += 256){
    int o = idx >> 7, hd = idx & 127;
    int h = hd >> 4, d = hd & 15;
    float acc = 0.f;
    #pragma unroll
    for (int c=0;c<16;c++) acc = fmaf(proj_w[o*128 + h*16 + c], A[h][c][d], acc);
    unsigned short hb = f2bf(acc);
    WeffH[(size_t)b*16384 + idx] = hb;
    WeffL[(size_t)b*16384 + idx] = f2bf(acc - bf2f(hb));
  }
}

// ---------------- 8x8 circular convolution, register-blocked ----------------
__global__ __launch_bounds__(256) void patch_circ_k(
    const float* __restrict__ vf, const float* __restrict__ kf, float* __restrict__ out)
{
  __shared__ float vs[32*68];
  __shared__ float ks2[32*68];
  size_t base = (size_t)blockIdx.y*HW + (size_t)blockIdx.x*2048;
  int t = threadIdx.x;
  #pragma unroll
  for (int it=0; it<2; it++){
    int idx = it*256 + t;
    int row = idx >> 6;
    int c4  = (idx & 63) << 2;
    float4 v  = *(const float4*)(vf + base + (size_t)row*256 + c4);
    float4 kv = *(const float4*)(kf + base + (size_t)row*256 + c4);
    int p = c4 >> 3, j0 = c4 & 7;
    *(float4*)&vs [p*68 + row*8 + j0] = v;
    *(float4*)&ks2[p*68 + row*8 + j0] = kv;
  }
  __syncthreads();
  int p = t & 31, pr = t >> 5;
  float acc[8];
  #pragma unroll
  for (int q=0;q<8;q++) acc[q]=0.f;
  #pragma unroll
  for (int i=0;i<8;i++){
    float4 va = *(float4*)&vs[p*68 + i*8];
    float4 vb = *(float4*)&vs[p*68 + i*8 + 4];
    int kr = (pr - i) & 7;
    float4 ka = *(float4*)&ks2[p*68 + kr*8];
    float4 kb = *(float4*)&ks2[p*68 + kr*8 + 4];
    float vv[8]={va.x,va.y,va.z,va.w,vb.x,vb.y,vb.z,vb.w};
    float kk[8]={ka.x,ka.y,ka.z,ka.w,kb.x,kb.y,kb.z,kb.w};
    #pragma unroll
    for (int q=0;q<8;q++)
      #pragma unroll
      for (int j=0;j<8;j++)
        acc[q] = fmaf(vv[j], kk[(q-j)&7], acc[q]);
  }
  float* op = out + base + (size_t)pr*256 + p*8;
  *(float4*)op     = make_float4(acc[0],acc[1],acc[2],acc[3]);
  *(float4*)(op+4) = make_float4(acc[4],acc[5],acc[6],acc[7]);
}

// ---------------- 256-pt Stockham FFT along rows ----------------
template<bool IN_REAL, bool OUT_REAL>
__global__ __launch_bounds__(64) void fft256_rows(
    const float* __restrict__ in, float* __restrict__ out, float dir, float scale)
{
  __shared__ float2 buf[2][256];
  __shared__ float2 tw[128];
  int t = threadIdx.x;
  size_t row = blockIdx.x;
  for (int i = t; i < 128; i += 64){
    float ang = 6.283185307179586477f * (float)i / 256.f;
    float s, c;
    sincosf(ang, &s, &c);
    tw[i] = make_float2(c, dir*s);
  }
  if (IN_REAL){
    const float* p = in + row*256;
    for (int i=t;i<256;i+=64) buf[0][i] = make_float2(p[i], 0.f);
  } else {
    const float2* p = ((const float2*)in) + row*256;
    for (int i=t;i<256;i+=64) buf[0][i] = p[i];
  }
  int cur = 0, m = 1;
  for (int st=0; st<8; st++){
    __syncthreads();
    #pragma unroll
    for (int p2=0;p2<2;p2++){
      int bf = t + (p2<<6);
      int k = bf & (m-1);
      int jm = bf - k;
      float2 a = buf[cur][k + jm];
      float2 c = buf[cur][k + jm + 128];
      float2 w = tw[jm];
      float2 sm = make_float2(a.x+c.x, a.y+c.y);
      float2 df = make_float2(a.x-c.x, a.y-c.y);
      buf[cur^1][k + 2*jm]     = sm;
      buf[cur^1][k + 2*jm + m] = cmul(w, df);
    }
    cur ^= 1; m <<= 1;
  }
  __syncthreads();
  if (OUT_REAL){
    float* p = out + row*256;
    for (int i=t;i<256;i+=64) p[i] = buf[cur][i].x * scale;
  } else {
    float2* p = ((float2*)out) + row*256;
    for (int i=t;i<256;i+=64){
      float2 v = buf[cur][i];
      p[i] = make_float2(v.x*scale, v.y*scale);
    }
  }
}

// ---------------- complex 256x256 per-plane transpose ----------------
__global__ __launch_bounds__(256) void transpose_c_k(
    const float2* __restrict__ in, float2* __restrict__ out)
{
  __shared__ float2 tile[32][33];
  int plane = blockIdx.z;
  int x0 = blockIdx.x*32, y0 = blockIdx.y*32;
  const float2* ip = in + (size_t)plane*HW;
  float2* op = out + (size_t)plane*HW;
  int tx = threadIdx.x & 31, ty = threadIdx.x >> 5;
  #pragma unroll
  for (int r=0;r<4;r++){
    int y = y0 + ty*4 + r;
    tile[ty*4+r][tx] = ip[(size_t)y*256 + x0 + tx];
  }
  __syncthreads();
  #pragma unroll
  for (int r=0;r<4;r++){
    int y = x0 + ty*4 + r;
    op[(size_t)y*256 + y0 + tx] = tile[tx][ty*4+r];
  }
}

// ---------------- channel LayerNorm * qf ----------------
__global__ __launch_bounds__(256) void ln_mul_k(
    const float* __restrict__ x, const float* __restrict__ qf,
    const float* __restrict__ lw, const float* __restrict__ lb,
    float* __restrict__ y)
{
  int b = blockIdx.y;
  size_t px0 = (size_t)blockIdx.x*64;
  int t = threadIdx.x;
  int px = t & 63, g = t >> 6;
  const float* xp = x + (size_t)b*8388608 + px0 + px;
  float vals[32];
  float s1 = 0.f, s2 = 0.f;
  #pragma unroll
  for (int i=0;i<32;i++){
    float v = xp[(size_t)(g*32+i)*HW];
    vals[i] = v; s1 += v; s2 += v*v;
  }
  __shared__ float r1[4][64], r2[4][64];
  r1[g][px] = s1; r2[g][px] = s2;
  __syncthreads();
  float S1 = r1[0][px]+r1[1][px]+r1[2][px]+r1[3][px];
  float S2 = r2[0][px]+r2[1][px]+r2[2][px]+r2[3][px];
  float mu = S1 * (1.f/128.f);
  float var = S2 * (1.f/128.f) - mu*mu;
  float rstd = rsqrtf(var + 1e-5f);
  const float* qp = qf + (size_t)b*8388608 + px0 + px;
  float* yp = y + (size_t)b*8388608 + px0 + px;
  #pragma unroll
  for (int i=0;i<32;i++){
    int c = g*32 + i;
    float v = (vals[i]-mu)*rstd*lw[c] + lb[c];
    yp[(size_t)c*HW] = v * qp[(size_t)c*HW];
  }
}

extern "C" void kernel_launch(void* const* d_in, const int* in_sizes, int n_in,
                              void* d_out, int out_size, void* d_ws, size_t ws_size,
                              hipStream_t stream)
{
  const float* x       = (const float*)d_in[0];
  const float* qkv_w   = (const float*)d_in[1];
  const float* qkv_dw  = (const float*)d_in[2];
  const float* proj_w  = (const float*)d_in[3];
  const float* q1_w    = (const float*)d_in[4];
  const float* q2_w    = (const float*)d_in[5];
  const float* kv_w    = (const float*)d_in[6];
  const float* kv_dw   = (const float*)d_in[7];
  const float* projf_w = (const float*)d_in[8];
  const float* temp    = (const float*)d_in[9];
  const float* ln_w    = (const float*)d_in[10];
  const float* ln_b    = (const float*)d_in[11];
  float* out = (float*)d_out;
  float* ws  = (float*)d_ws;

  const size_t P  = 33554432;   // 4*128*65536 floats
  const size_t CB = 8388608;    // per-batch stride
  float* A = ws;
  float* B = ws + P;
  float* C = ws + 2*P;
  float* rnorm = ws + 3*P;                 // 1024
  float* Gp    = rnorm + 1024;             // 524288
  unsigned short* WHp   = (unsigned short*)(Gp + 524288);  // 131072 shorts
  unsigned short* WLp   = WHp + 131072;
  unsigned short* WeffH = WLp + 131072;    // 65536 shorts
  unsigned short* WeffL = WeffH + 65536;

  dim3 cg(128,1,4); dim3 cb(256);          // 512-px blocks
  dim3 dg(512,8);  dim3 db(256);

  // ---- weight prep ----
  wprep_k<<<512,256,0,stream>>>(qkv_w, kv_w, q1_w, q2_w, projf_w, WHp, WLp);
  // ---- q ----
  convT_mfma<<<cg,cb,0,stream>>>(x, CB, WHp + 0*16384, WLp + 0*16384, 0, A, CB, nullptr, 0, 0);
  dwconv3_row_k<<<dg,db,0,stream>>>(A, qkv_dw + 0*1152, out);    // q = out
  colnorm_k<<<dim3(128,4),256,0,stream>>>(out, rnorm, 0);
  // ---- k ----
  convT_mfma<<<cg,cb,0,stream>>>(x, CB, WHp + 1*16384, WLp + 1*16384, 0, B, CB, nullptr, 0, 0);
  dwconv3_row_k<<<dg,db,0,stream>>>(B, qkv_dw + 1*1152, A);      // k = A
  colnorm_k<<<dim3(128,4),256,0,stream>>>(A, rnorm, 128);
  qk_gram_k<<<dim3(64,8,4),256,0,stream>>>(out, A, Gp);
  attn_weff_k<<<4,256,0,stream>>>(Gp, rnorm, temp, proj_w, WeffH, WeffL);
  // ---- v ----
  convT_mfma<<<cg,cb,0,stream>>>(x, CB, WHp + 2*16384, WLp + 2*16384, 0, B, CB, nullptr, 0, 0);
  dwconv3_row_k<<<dg,db,0,stream>>>(B, qkv_dw + 2*1152, C);      // v = C
  // ---- attn out = Weff @ v -> B ----
  convT_mfma<<<cg,cb,0,stream>>>(C, CB, WeffH, WeffL, 16384, B, CB, nullptr, 0, 0);
  // ---- kf ----
  convT_mfma<<<cg,cb,0,stream>>>(B, CB, WHp + 3*16384, WLp + 3*16384, 0, A, CB, nullptr, 0, 0);
  dwconv3_row_k<<<dg,db,0,stream>>>(A, kv_dw + 0*1152, out);     // kf = out
  // ---- vf ----
  convT_mfma<<<cg,cb,0,stream>>>(B, CB, WHp + 4*16384, WLp + 4*16384, 0, A, CB, nullptr, 0, 0);
  dwconv3_row_k<<<dg,db,0,stream>>>(A, kv_dw + 1*1152, C);       // vf = C
  // ---- patch circular conv -> out_1 = A ----
  patch_circ_k<<<dim3(32,512),256,0,stream>>>(C, out, A);
  // ---- forward FFT: x -> x_fftT in out (C as scratch) ----
  for (int b=0;b<4;b++){
    fft256_rows<true,false><<<32768,64,0,stream>>>(x + (size_t)b*CB, C, -1.f, 1.f);
    transpose_c_k<<<dim3(8,8,128),256,0,stream>>>((const float2*)C, (float2*)(C + P/2));
    fft256_rows<false,true><<<32768,64,0,stream>>>(C + P/2, out + (size_t)b*CB, -1.f, 1.f);
  }
  // ---- gating convs ----
  convT_mfma<<<cg,cb,0,stream>>>(out, CB, WHp + 5*16384, WLp + 5*16384, 0, C, CB, nullptr, 0, 1);
  convT_mfma<<<cg,cb,0,stream>>>(C, CB, WHp + 6*16384, WLp + 6*16384, 0, out, CB, nullptr, 0, 0);
  // ---- inverse FFT: x_fft3T (out) -> qf (out) ----
  for (int b=0;b<4;b++){
    fft256_rows<true,false><<<32768,64,0,stream>>>(out + (size_t)b*CB, C, 1.f, 1.f/256.f);
    transpose_c_k<<<dim3(8,8,128),256,0,stream>>>((const float2*)C, (float2*)(C + P/2));
    fft256_rows<false,true><<<32768,64,0,stream>>>(C + P/2, out + (size_t)b*CB, 1.f, 1.f/256.f);
  }
  // ---- LayerNorm(out_1=A) * qf(out) -> C ----
  ln_mul_k<<<dim3(1024,4),256,0,stream>>>(A, out, ln_w, ln_b, C);
  // ---- final conv + residual (R = B = attn out) ----
  convT_mfma<<<cg,cb,0,stream>>>(C, CB, WHp + 7*16384, WLp + 7*16384, 0, out, CB, B, CB, 0);
}